// Round 8
// baseline (2439.715 us; speedup 1.0000x reference)
//
#include <hip/hip_runtime.h>
#include <math.h>

#pragma clang fp contract(off)

namespace {

constexpr int kSteps = 32;

// ---- workspace layout (float slots) ----
constexpr size_t OFF_TEMPS = 0;        // 32 floats
constexpr size_t OFF_KEYS  = 64;       // 194 u32
constexpr size_t OFF_WQ    = 512;      // 65536 (float4: 4 cols per k, H phase)
constexpr size_t OFF_WTQ   = 66048;    // 65536 (same for W^T, AV phase)
constexpr size_t OFF_F2T   = 131584;   // 65536
constexpr size_t OFF_X1    = 197120;   // 524288
constexpr size_t OFF_BMOD  = 721408;   // 2097152
constexpr size_t OFF_CMOD  = 2818560;  // 2097152
constexpr size_t WS_FLOATS = 4915712;  // ~19.7 MB

// ================= threefry2x32 (JAX semantics) =================
__device__ __forceinline__ unsigned rotl32(unsigned v, int n) {
  return (v << n) | (v >> (32 - n));
}

__device__ __forceinline__ void tf_block(unsigned k0, unsigned k1,
                                         unsigned c0, unsigned c1,
                                         unsigned* o0, unsigned* o1) {
  unsigned k2 = k0 ^ k1 ^ 0x1BD11BDAu;
  unsigned x0 = c0 + k0;
  unsigned x1 = c1 + k1;
  x0 += x1; x1 = rotl32(x1, 13); x1 ^= x0;
  x0 += x1; x1 = rotl32(x1, 15); x1 ^= x0;
  x0 += x1; x1 = rotl32(x1, 26); x1 ^= x0;
  x0 += x1; x1 = rotl32(x1, 6);  x1 ^= x0;
  x0 += k1; x1 += k2 + 1u;
  x0 += x1; x1 = rotl32(x1, 17); x1 ^= x0;
  x0 += x1; x1 = rotl32(x1, 29); x1 ^= x0;
  x0 += x1; x1 = rotl32(x1, 16); x1 ^= x0;
  x0 += x1; x1 = rotl32(x1, 24); x1 ^= x0;
  x0 += k2; x1 += k0 + 2u;
  x0 += x1; x1 = rotl32(x1, 13); x1 ^= x0;
  x0 += x1; x1 = rotl32(x1, 15); x1 ^= x0;
  x0 += x1; x1 = rotl32(x1, 26); x1 ^= x0;
  x0 += x1; x1 = rotl32(x1, 6);  x1 ^= x0;
  x0 += k0; x1 += k1 + 3u;
  x0 += x1; x1 = rotl32(x1, 17); x1 ^= x0;
  x0 += x1; x1 = rotl32(x1, 29); x1 ^= x0;
  x0 += x1; x1 = rotl32(x1, 16); x1 ^= x0;
  x0 += x1; x1 = rotl32(x1, 24); x1 ^= x0;
  x0 += k1; x1 += k2 + 4u;
  x0 += x1; x1 = rotl32(x1, 13); x1 ^= x0;
  x0 += x1; x1 = rotl32(x1, 15); x1 ^= x0;
  x0 += x1; x1 = rotl32(x1, 26); x1 ^= x0;
  x0 += x1; x1 = rotl32(x1, 6);  x1 ^= x0;
  x0 += k2; x1 += k0 + 5u;
  *o0 = x0; *o1 = x1;
}

__device__ __forceinline__ float tf_uniform(unsigned k0, unsigned k1, unsigned idx) {
  unsigned o0, o1;
  tf_block(k0, k1, 0u, idx, &o0, &o1);
  unsigned bits = o0 ^ o1;
  float f = __uint_as_float((bits >> 9) | 0x3f800000u);
  return f - 1.0f;
}

// XLA EmitFastTanh (f32), plain mul/add.
__device__ __forceinline__ float xla_tanhf(float x) {
  if (fabsf(x) < 0.0004f) return x;
  float xc = fminf(fmaxf(x, -9.0f), 9.0f);
  float x2 = xc * xc;
  float num = -2.76076847742355e-16f;
  num = num * x2 + 2.00018790482477e-13f;
  num = num * x2 + -8.60467152213735e-11f;
  num = num * x2 + 5.12229709037114e-08f;
  num = num * x2 + 1.48572235717979e-05f;
  num = num * x2 + 6.37261928875436e-04f;
  num = num * x2 + 4.89352455891786e-03f;
  num = xc * num;
  float den = 1.19825839466702e-06f;
  den = den * x2 + 1.18534705686654e-04f;
  den = den * x2 + 2.26843463243900e-03f;
  den = den * x2 + 4.89352518554385e-03f;
  return num / den;
}

// XLA elemental kLogistic: 0.5 + 0.5 * tanh(0.5 * x)
__device__ __forceinline__ float xla_sigmoid(float x) {
  return 0.5f + 0.5f * xla_tanhf(0.5f * x);
}

// ---- packed f32 FMA (VOP3P, full rate, IEEE-exact per half) ----
// pk_fma_lo: broadcast xs.lo  -> {fma(xs.lo,w.lo,a.lo), fma(xs.lo,w.hi,a.hi)}
// pk_fma_hi: broadcast xs.hi  -> {fma(xs.hi,w.lo,a.lo), fma(xs.hi,w.hi,a.hi)}
__device__ __forceinline__ float2 pk_fma_lo(float2 xs, float2 w, float2 a) {
  float2 d;
  asm("v_pk_fma_f32 %0, %1, %2, %3 op_sel:[0,0,0] op_sel_hi:[0,1,1]"
      : "=v"(d) : "v"(xs), "v"(w), "v"(a));
  return d;
}
__device__ __forceinline__ float2 pk_fma_hi(float2 xs, float2 w, float2 a) {
  float2 d;
  asm("v_pk_fma_f32 %0, %1, %2, %3 op_sel:[1,0,0] op_sel_hi:[1,1,1]"
      : "=v"(d) : "v"(xs), "v"(w), "v"(a));
  return d;
}

// ================= setup kernels =================
__global__ __launch_bounds__(64) void kInitMeta(float* temps, unsigned* keys) {
  int t = threadIdx.x;
  if (t < 32) {
    float tf = (float)t;
    float arg = 0.1f * (tf - 16.0f);
    float e = (float)exp((double)arg);  // constant-folded by XLA w/ host expf
    float s = 1.0f / (1.0f + e);
    temps[t] = 1.0f + 4.0f * s;
  }
  if (t == 0) {
    unsigned cur0 = 0u, cur1 = 42u;  // jax.random.key(42)
    unsigned a0, a1, b0, b1;
    tf_block(cur0, cur1, 0u, 0u, &a0, &a1);  // carried key
    tf_block(cur0, cur1, 0u, 1u, &b0, &b1);  // init-v key
    keys[0] = b0; keys[1] = b1;
    cur0 = a0; cur1 = a1;
    for (int st = 0; st < kSteps; ++st) {
      unsigned n0, n1, kh0, kh1, ks0a, ks0b, kv0, kv1;
      tf_block(cur0, cur1, 0u, 0u, &n0, &n1);
      tf_block(cur0, cur1, 0u, 1u, &kh0, &kh1);
      tf_block(cur0, cur1, 0u, 2u, &ks0a, &ks0b);
      tf_block(cur0, cur1, 0u, 3u, &kv0, &kv1);
      keys[2 + st * 6 + 0] = kh0;  keys[2 + st * 6 + 1] = kh1;
      keys[2 + st * 6 + 2] = ks0a; keys[2 + st * 6 + 3] = ks0b;
      keys[2 + st * 6 + 4] = kv0;  keys[2 + st * 6 + 5] = kv1;
      cur0 = n0; cur1 = n1;
    }
  }
}

// Wq[(k)*64 + jj] = {W[k][jj], W[k][jj+64], W[k][jj+128], W[k][jj+192]}
__global__ __launch_bounds__(256) void kWq(const float* __restrict__ W, float4* __restrict__ Wq) {
  int idx = blockIdx.x * 256 + threadIdx.x;  // 16384 float4
  int k = idx >> 6, jj = idx & 63;
  float4 w;
  w.x = W[k * 256 + jj];
  w.y = W[k * 256 + jj + 64];
  w.z = W[k * 256 + jj + 128];
  w.w = W[k * 256 + jj + 192];
  Wq[idx] = w;
}

// Wtq[(k)*64 + jj] = {W[jj][k], W[jj+64][k], W[jj+128][k], W[jj+192][k]}
__global__ __launch_bounds__(256) void kWtq(const float* __restrict__ W, float4* __restrict__ Wtq) {
  int idx = blockIdx.x * 256 + threadIdx.x;  // 16384 float4
  int k = idx >> 6, jj = idx & 63;
  float4 w;
  w.x = W[jj * 256 + k];
  w.y = W[(jj + 64) * 256 + k];
  w.z = W[(jj + 128) * 256 + k];
  w.w = W[(jj + 192) * 256 + k];
  Wtq[idx] = w;
}

__global__ __launch_bounds__(256) void kTf2(const float* __restrict__ fc2w, float* __restrict__ fc2wT) {
  int idx = blockIdx.x * 256 + threadIdx.x;  // 65536
  int k = idx >> 10, o = idx & 1023;
  fc2wT[idx] = fc2w[o * 64 + k];             // fc2wT[k][o]
}

__global__ __launch_bounds__(256) void kX1(const float* __restrict__ cond,
                                           const float* __restrict__ fc1w,
                                           const float* __restrict__ fc1b,
                                           float* __restrict__ x1) {
  int idx = blockIdx.x * 256 + threadIdx.x;  // 524288
  int b = idx >> 6, hh = idx & 63;
  float acc = 0.0f;
  for (int k = 0; k < 16; ++k)
    acc = acc + cond[b * 16 + k] * fc1w[hh * 16 + k];
  acc = acc + fc1b[hh];
  x1[idx] = xla_tanhf(acc);
}

// coalesced via fc2wT; same op order as the passing kMod
__global__ __launch_bounds__(256) void kMod2(const float* __restrict__ x1,
                                             const float* __restrict__ fc2wT,
                                             const float* __restrict__ fc2b,
                                             const float* __restrict__ bvec,
                                             const float* __restrict__ cvec,
                                             float* __restrict__ bmod,
                                             float* __restrict__ cmod) {
  const int bid = blockIdx.x;        // 16384
  const int b = bid >> 1;
  const int half = bid & 1;
  const int ii = threadIdx.x;
  const int og = half * 512 + ii;
  const int ob = og + 256;
  float dg = 0.0f, db = 0.0f;
  for (int k = 0; k < 64; ++k) {
    float xv = x1[b * 64 + k];
    dg = dg + xv * fc2wT[k * 1024 + og];
    db = db + xv * fc2wT[k * 1024 + ob];
  }
  dg = dg + fc2b[og];
  db = db + fc2b[ob];
  float base = half ? cvec[ii] : bvec[ii];
  float outv = (1.0f + dg) * base + db;
  if (half) cmod[b * 256 + ii] = outv;
  else      bmod[b * 256 + ii] = outv;
}

// ================= fused 32-step Gibbs kernel =================
// 4096 blocks x 64 threads (single wave). Each thread: 2 rows x 4 cols
// (j0, +64, +128, +192). No barriers (program-order LDS within a wave,
// validated in R5). MAC uses v_pk_fma_f32: 2 IEEE-exact FMAs/instr; each
// column chain stays ascending-k with one rounding per term -> bit-exact.
__global__ __launch_bounds__(64, 4) void kGibbs(
    const float4* __restrict__ Wq, const float4* __restrict__ Wtq,
    const float* __restrict__ bmod, const float* __restrict__ cmod,
    const unsigned* __restrict__ keys, const float* __restrict__ temps,
    float* __restrict__ out) {
  __shared__ float4 X4[2][65];       // veff -> h -> a (row stride 260 floats)
  __shared__ float4 V4[2][65];       // v
  __shared__ float4 BM4[2][65];      // bmod rows (bsum + vb chain)
  __shared__ float  chainres[6];
  __shared__ float  bsum_s[2];
  __shared__ int    s0i[2];

  float* Xf  = reinterpret_cast<float*>(X4);
  float* Vf  = reinterpret_cast<float*>(V4);
  float* BMf = reinterpret_cast<float*>(BM4);

  const int j0 = threadIdx.x;        // 0..63
  const int brow = blockIdx.x * 2;

  float bmv[2][4], cmv[2][4];
  {
    const unsigned k00 = keys[0], k01 = keys[1];
#pragma unroll
    for (int r = 0; r < 2; ++r)
#pragma unroll
      for (int c = 0; c < 4; ++c) {
        const int j = j0 + 64 * c;
        const int gi = (brow + r) * 256 + j;
        float bm = bmod[gi];
        bmv[r][c] = bm; cmv[r][c] = cmod[gi];
        BMf[r * 260 + j] = bm;
        float u = tf_uniform(k00, k01, (unsigned)gi);
        float vv = (u < 0.5f) ? 1.0f : 0.0f;
        Vf[r * 260 + j] = vv;
        Xf[r * 260 + j] = vv;        // veff at t=0 (s0=1)
      }
  }
  if (j0 < 2) s0i[j0] = 1;
  if (j0 < 2) {  // bsum per row, sequential ascending plain adds (exact)
    const float* B = BMf + j0 * 260;
    float s = 0.0f;
    for (int k = 0; k < 256; ++k) s = s + B[k];
    bsum_s[j0] = s;
  }

  for (int t = 0; t < kSteps; ++t) {
    const float T = temps[t];
    const unsigned kh0 = keys[2 + t * 6 + 0], kh1 = keys[2 + t * 6 + 1];
    const unsigned ksa = keys[2 + t * 6 + 2], ksb = keys[2 + t * 6 + 3];
    const unsigned kv0 = keys[2 + t * 6 + 4], kv1 = keys[2 + t * 6 + 5];

    // ---- H MAC: per col j: sum_k veff[r][k]*W[k][j], ascending k ----
    float2 aA[2], aB[2];   // aA = cols(0,1), aB = cols(2,3)
#pragma unroll
    for (int r = 0; r < 2; ++r) {
      aA[r] = make_float2(0.0f, 0.0f);
      aB[r] = make_float2(0.0f, 0.0f);
    }
    for (int kb = 0; kb < 64; ++kb) {
      const int base = (kb << 8) + j0;   // (4kb+u)*64 + j0, u=0..3
      float4 w0 = Wq[base];
      float4 w1 = Wq[base + 64];
      float4 w2 = Wq[base + 128];
      float4 w3 = Wq[base + 192];
#pragma unroll
      for (int r = 0; r < 2; ++r) {
        float4 x = X4[r][kb];
        float2 xy = make_float2(x.x, x.y);
        float2 zw = make_float2(x.z, x.w);
        aA[r] = pk_fma_lo(xy, make_float2(w0.x, w0.y), aA[r]);  // k=4kb+0
        aB[r] = pk_fma_lo(xy, make_float2(w0.z, w0.w), aB[r]);
        aA[r] = pk_fma_hi(xy, make_float2(w1.x, w1.y), aA[r]);  // k=4kb+1
        aB[r] = pk_fma_hi(xy, make_float2(w1.z, w1.w), aB[r]);
        aA[r] = pk_fma_lo(zw, make_float2(w2.x, w2.y), aA[r]);  // k=4kb+2
        aB[r] = pk_fma_lo(zw, make_float2(w2.z, w2.w), aB[r]);
        aA[r] = pk_fma_hi(zw, make_float2(w3.x, w3.y), aA[r]);  // k=4kb+3
        aB[r] = pk_fma_hi(zw, make_float2(w3.z, w3.w), aB[r]);
      }
    }

    // ---- h draws -> X (overwrites veff; single wave = program order) ----
#pragma unroll
    for (int r = 0; r < 2; ++r) {
      float av[4] = {aA[r].x, aA[r].y, aB[r].x, aB[r].y};
#pragma unroll
      for (int c = 0; c < 4; ++c) {
        const int j = j0 + 64 * c;
        float z = (av[c] + cmv[r][c]) / T;
        float p = xla_sigmoid(z);
        float u = tf_uniform(kh0, kh1, (unsigned)((brow + r) * 256 + j));
        Xf[r * 260 + j] = (u < p) ? 1.0f : 0.0f;
      }
    }

    // ---- AV MAC: per col i: sum_k h[r][k]*W[i][k], ascending k ----
#pragma unroll
    for (int r = 0; r < 2; ++r) {
      aA[r] = make_float2(0.0f, 0.0f);
      aB[r] = make_float2(0.0f, 0.0f);
    }
    for (int kb = 0; kb < 64; ++kb) {
      const int base = (kb << 8) + j0;
      float4 w0 = Wtq[base];
      float4 w1 = Wtq[base + 64];
      float4 w2 = Wtq[base + 128];
      float4 w3 = Wtq[base + 192];
#pragma unroll
      for (int r = 0; r < 2; ++r) {
        float4 x = X4[r][kb];
        float2 xy = make_float2(x.x, x.y);
        float2 zw = make_float2(x.z, x.w);
        aA[r] = pk_fma_lo(xy, make_float2(w0.x, w0.y), aA[r]);
        aB[r] = pk_fma_lo(xy, make_float2(w0.z, w0.w), aB[r]);
        aA[r] = pk_fma_hi(xy, make_float2(w1.x, w1.y), aA[r]);
        aB[r] = pk_fma_hi(xy, make_float2(w1.z, w1.w), aB[r]);
        aA[r] = pk_fma_lo(zw, make_float2(w2.x, w2.y), aA[r]);
        aB[r] = pk_fma_lo(zw, make_float2(w2.z, w2.w), aB[r]);
        aA[r] = pk_fma_hi(zw, make_float2(w3.x, w3.y), aA[r]);
        aB[r] = pk_fma_hi(zw, make_float2(w3.z, w3.w), aB[r]);
      }
    }

    // ---- spill a -> X ; v candidate draws (independent of s0) ----
    float ve2[2][4];
#pragma unroll
    for (int r = 0; r < 2; ++r) {
      float av[4] = {aA[r].x, aA[r].y, aB[r].x, aB[r].y};
#pragma unroll
      for (int c = 0; c < 4; ++c) {
        const int j = j0 + 64 * c;
        Xf[r * 260 + j] = av[c];
        float z = (av[c] + bmv[r][c]) / T;
        float p = xla_sigmoid(z);
        float u = tf_uniform(kv0, kv1, (unsigned)((brow + r) * 256 + j));
        ve2[r][c] = (u < p) ? 1.0f : 0.0f;
      }
    }

    // ---- chains (lanes 0..5): r=lane/3, c=lane%3; float4 reads ----
    // c0: vb = sum v*bm; c1: va = sum v*a; c2: as = sum a (ascending, exact)
    if (j0 < 6) {
      const int r = j0 / 3, c = j0 % 3;
      const float4* A4c = reinterpret_cast<const float4*>(Vf + r * 260);
      const float4* Y4c = reinterpret_cast<const float4*>(
          ((c == 0) ? BMf : Xf) + r * 260);
      const bool isAs = (c == 2);
      float s = 0.0f;
      for (int q = 0; q < 64; ++q) {
        float4 a4 = A4c[q];
        float4 y4 = Y4c[q];
        float m0 = isAs ? 1.0f : a4.x; s = __builtin_fmaf(m0, y4.x, s);
        float m1 = isAs ? 1.0f : a4.y; s = __builtin_fmaf(m1, y4.y, s);
        float m2 = isAs ? 1.0f : a4.z; s = __builtin_fmaf(m2, y4.z, s);
        float m3 = isAs ? 1.0f : a4.w; s = __builtin_fmaf(m3, y4.w, s);
      }
      chainres[j0] = s;
    }

    // ---- s0 draw (lanes 0..1) ----
    if (j0 < 2) {
      const int r = j0;
      float vb = chainres[3 * r], va = chainres[3 * r + 1], as = chainres[3 * r + 2];
      float dE = ((-bsum_s[r] - as) + 2.0f * vb) + 2.0f * va;
      float z = dE / T;
      float p = xla_sigmoid(z);
      float u = tf_uniform(ksa, ksb, (unsigned)(brow + r));
      s0i[r] = (u < p) ? 1 : 0;
    }

    // ---- v_next = s0 ? ve2 : 1-ve2 ; veff(t+1) == ve2 (double-flip) ----
#pragma unroll
    for (int r = 0; r < 2; ++r) {
      int s0r = s0i[r];
#pragma unroll
      for (int c = 0; c < 4; ++c) {
        const int j = j0 + 64 * c;
        float e = ve2[r][c];
        Vf[r * 260 + j] = s0r ? e : 1.0f - e;
        Xf[r * 260 + j] = e;
      }
    }
  }

#pragma unroll
  for (int r = 0; r < 2; ++r)
#pragma unroll
    for (int c = 0; c < 4; ++c) {
      const int j = j0 + 64 * c;
      out[(brow + r) * 256 + j] = Vf[r * 260 + j];
    }
  if (blockIdx.x == 0 && j0 < 32) out[2097152 + j0] = temps[j0];
}

}  // namespace

extern "C" void kernel_launch(void* const* d_in, const int* in_sizes, int n_in,
                              void* d_out, int out_size, void* d_ws, size_t ws_size,
                              hipStream_t stream) {
  (void)in_sizes; (void)n_in; (void)out_size;
  const float* cond = (const float*)d_in[0];
  const float* W    = (const float*)d_in[1];
  const float* bvec = (const float*)d_in[2];
  const float* cvec = (const float*)d_in[3];
  const float* fc1w = (const float*)d_in[4];
  const float* fc1b = (const float*)d_in[5];
  const float* fc2w = (const float*)d_in[6];
  const float* fc2b = (const float*)d_in[7];

  if (ws_size < WS_FLOATS * sizeof(float)) return;

  float* ws      = (float*)d_ws;
  float* temps   = ws + OFF_TEMPS;
  unsigned* keys = (unsigned*)(ws + OFF_KEYS);
  float4* Wq     = (float4*)(ws + OFF_WQ);
  float4* Wtq    = (float4*)(ws + OFF_WTQ);
  float* fc2wT   = ws + OFF_F2T;
  float* x1      = ws + OFF_X1;
  float* bmod    = ws + OFF_BMOD;
  float* cmod    = ws + OFF_CMOD;
  float* out     = (float*)d_out;

  hipLaunchKernelGGL(kInitMeta, dim3(1), dim3(64), 0, stream, temps, keys);
  hipLaunchKernelGGL(kWq, dim3(64), dim3(256), 0, stream, W, Wq);
  hipLaunchKernelGGL(kWtq, dim3(64), dim3(256), 0, stream, W, Wtq);
  hipLaunchKernelGGL(kTf2, dim3(256), dim3(256), 0, stream, fc2w, fc2wT);
  hipLaunchKernelGGL(kX1, dim3(2048), dim3(256), 0, stream, cond, fc1w, fc1b, x1);
  hipLaunchKernelGGL(kMod2, dim3(16384), dim3(256), 0, stream, x1, fc2wT, fc2b, bvec, cvec, bmod, cmod);
  hipLaunchKernelGGL(kGibbs, dim3(4096), dim3(64), 0, stream, Wq, Wtq, bmod, cmod, keys, temps, out);
}